// Round 8
// baseline (340.354 us; speedup 1.0000x reference)
//
#include <hip/hip_runtime.h>
#include <hip/hip_fp16.h>

#define D_IN   128
#define HEADS  8
#define FOUT   64
#define NOUT   16     // 8 src + 8 trg folded outputs
#define NPB    128    // nodes per bin (local index fits in 7 bits)
#define NB_MAX 1024   // max bins
#define CHUNK  4096   // edges per histogram/scatter block
#define NBLK_MAX 1024 // max blocks in pass A/C (scan width)
#define TPN    8      // threads per node in k_nodesum
#define SROWS  64     // nodes per k_scores tile
#define SPAD   129    // padded LDS row stride (floats)

typedef unsigned __attribute__((ext_vector_type(2))) uint2v;
typedef float    __attribute__((ext_vector_type(4))) float4v;

// -------------------------------- helpers -----------------------------------
__device__ __forceinline__ unsigned pack2(float a, float b) {
    union { __half2 h; unsigned u; } c;
    c.h = __floats2half2_rn(a, b);
    return c.u;
}
__device__ __forceinline__ float2 up2(unsigned u) {
    union { unsigned x; __half2 h; } c;
    c.x = u;
    return __half22float2(c.h);
}

// streaming (non-temporal) access: keep L2 for the gather hot-set
__device__ __forceinline__ unsigned ntl_u(const unsigned* p) {
    return __builtin_nontemporal_load(p);
}
__device__ __forceinline__ uint2v ntl_u2(const unsigned* p) {
    return __builtin_nontemporal_load((const uint2v*)p);
}
__device__ __forceinline__ float4v ntl_f4(const float* p) {
    return __builtin_nontemporal_load((const float4v*)p);
}
__device__ __forceinline__ void nts_u(unsigned* p, unsigned v) {
    __builtin_nontemporal_store(v, p);
}
__device__ __forceinline__ void nts_f4(float* p, float4v v) {
    __builtin_nontemporal_store(v, (float4v*)p);
}

// ---------------------------------------------------------------------------
// int32 vs int64 edge_index detection (sampled): if int64 (LE), odd 32-bit
// words are zero high-halves.  flag==0 -> int64 ; flag!=0 -> int32.
// flag is zeroed by k_fold_w (launched before this on the same stream).
__global__ void k_detect(const unsigned int* __restrict__ idx_w, int nwords,
                         unsigned int* __restrict__ flag) {
    unsigned int local = 0;
    int stride = gridDim.x * blockDim.x;
    for (int i = blockIdx.x * blockDim.x + threadIdx.x; 2 * i + 1 < nwords; i += stride)
        local |= idx_w[2 * i + 1];
    if (__any(local != 0) && (threadIdx.x & 63) == 0)
        atomicOr(flag, 1u);
}

__device__ __forceinline__ void load_edge(const unsigned int* idx, int e, int E,
                                          bool is64, unsigned int& s, unsigned int& t) {
    if (is64) {
        uint2v a = ntl_u2(idx + 2 * (size_t)e);
        uint2v b = ntl_u2(idx + 2 * ((size_t)E + e));
        s = a.x; t = b.x;
    } else {
        s = ntl_u(idx + e);
        t = ntl_u(idx + (size_t)E + e);
    }
}

__device__ __forceinline__ unsigned int load_trg(const unsigned int* idx, int e, int E,
                                                 bool is64) {
    if (is64) { uint2v b = ntl_u2(idx + 2 * ((size_t)E + e)); return b.x; }
    return ntl_u(idx + (size_t)E + e);
}

// ---------------------------------------------------------------------------
// Fold scoring vectors into the projection. Wc layout: [16 outputs][128 d].
// Also zeroes the detection flag (replaces a hipMemsetAsync that cost ~60us
// of GPU time per graph replay as a fillBufferAligned dispatch).
__global__ void k_fold_w(const float* __restrict__ W,
                         const float* __restrict__ a_src,
                         const float* __restrict__ a_trg,
                         float* __restrict__ Wc,
                         unsigned int* __restrict__ flag) {
    int t = blockIdx.x * blockDim.x + threadIdx.x;
    if (t == 0) *flag = 0u;
    if (t >= D_IN * HEADS) return;
    int d = t >> 3, h = t & 7;
    const float* wrow = W + d * (HEADS * FOUT) + h * FOUT;
    float s1 = 0.f, s2 = 0.f;
    #pragma unroll 4
    for (int f = 0; f < FOUT; ++f) {
        float w = wrow[f];
        s1 += w * a_src[h * FOUT + f];
        s2 += w * a_trg[h * FOUT + f];
    }
    Wc[h * D_IN + d]           = s1;
    Wc[(HEADS + h) * D_IN + d] = s2;
}

// ---------------------------------------------------------------------------
// Per-node scores, shuffle-free: stage 64 X-rows in LDS (stride-129 pad),
// thread (r, og) computes outputs og*4..og*4+3 for node r.
__global__ void k_scores_t(const float* __restrict__ x,
                           const float* __restrict__ Wc,
                           float* __restrict__ ssrc_f,
                           float* __restrict__ strg_f,
                           __half* __restrict__ ssrc_h, int N) {
    __shared__ float xt[SROWS * SPAD];
    int node0 = blockIdx.x * SROWS;
    int tid   = threadIdx.x;
    int nrows = min(SROWS, N - node0);

    for (int i = tid; i < nrows * 32; i += 256) {
        int r = i >> 5, c = (i & 31) * 4;
        float4v v = ntl_f4(x + (size_t)(node0 + r) * D_IN + c);
        float* dst = &xt[r * SPAD + c];
        dst[0] = v.x; dst[1] = v.y; dst[2] = v.z; dst[3] = v.w;
    }
    __syncthreads();

    int r  = tid & 63;
    int og = tid >> 6;          // wave-uniform output group (4 outputs)
    if (r >= nrows) return;
    int n = node0 + r;

    const float* w = Wc + og * 4 * D_IN;
    float a0 = 0.f, a1 = 0.f, a2 = 0.f, a3 = 0.f;
    const float* xr = &xt[r * SPAD];
    #pragma unroll 8
    for (int d = 0; d < D_IN; ++d) {
        float xv = xr[d];
        a0 += xv * w[d];
        a1 += xv * w[D_IN + d];
        a2 += xv * w[2 * D_IN + d];
        a3 += xv * w[3 * D_IN + d];
    }

    float4 res = make_float4(a0, a1, a2, a3);
    if (og < 2) *(float4*)(ssrc_f + (size_t)n * HEADS + og * 4)       = res;
    else        *(float4*)(strg_f + (size_t)n * HEADS + (og - 2) * 4) = res;
    if (og < 2) {
        uint2 hp;
        hp.x = pack2(a0, a1);
        hp.y = pack2(a2, a3);
        *(uint2*)(ssrc_h + (size_t)n * HEADS + og * 4) = hp;
    }
}

// ---------------------------------------------------------------------------
// Pass A: per-block LDS histogram of coarse bins; write bin-major histB.
__global__ void k_hist(const unsigned int* __restrict__ idx, int E,
                       const unsigned int* __restrict__ flag,
                       int* __restrict__ histB, int NB, int NBLK) {
    __shared__ int h[NB_MAX];
    for (int i = threadIdx.x; i < NB; i += blockDim.x) h[i] = 0;
    __syncthreads();
    bool is64 = (*flag == 0u);
    int base = blockIdx.x * CHUNK;
    int lim  = min(base + CHUNK, E);
    for (int e = base + threadIdx.x; e < lim; e += blockDim.x) {
        unsigned int t = load_trg(idx, e, E, is64);
        atomicAdd(&h[t >> 7], 1);
    }
    __syncthreads();
    for (int i = threadIdx.x; i < NB; i += blockDim.x)
        histB[(size_t)i * NBLK + blockIdx.x] = h[i];
}

// Pass B1: per-bin exclusive scan over blocks (coalesced histB row read);
// exclusive offsets scattered into block-major histA; per-bin totals out.
__global__ void k_scan_blocks(const int* __restrict__ histB,
                              int* __restrict__ histA, int NB, int NBLK,
                              int* __restrict__ binTotal) {
    int b = blockIdx.x;
    __shared__ int v[NBLK_MAX];
    int tid = threadIdx.x;
    v[tid] = (tid < NBLK) ? histB[(size_t)b * NBLK + tid] : 0;
    __syncthreads();
    for (int off = 1; off < NBLK_MAX; off <<= 1) {
        int t = (tid >= off) ? v[tid - off] : 0;
        __syncthreads();
        v[tid] += t;
        __syncthreads();
    }
    if (tid < NBLK)
        histA[(size_t)tid * NB + b] = tid ? v[tid - 1] : 0;
    if (tid == 0)
        binTotal[b] = v[NBLK_MAX - 1];
}

// Pass B2: exclusive scan over bins. single block.
__global__ void k_scan_bins(const int* __restrict__ binTotal, int NB,
                            int* __restrict__ binBase) {
    __shared__ int v[NB_MAX];
    int tid = threadIdx.x;
    v[tid] = (tid < NB) ? binTotal[tid] : 0;
    __syncthreads();
    for (int off = 1; off < NB_MAX; off <<= 1) {
        int t = (tid >= off) ? v[tid - off] : 0;
        __syncthreads();
        v[tid] += t;
        __syncthreads();
    }
    if (tid < NB)
        binBase[tid] = tid ? v[tid - 1] : 0;
}

// Pass C: scatter packed edge records into bin order.
// record = src | (trg & 127) << 20   (needs N < 2^20)
__global__ void k_scatter(const unsigned int* __restrict__ idx, int E,
                          const unsigned int* __restrict__ flag,
                          const int* __restrict__ histA, int NB,
                          const int* __restrict__ binBase,
                          unsigned int* __restrict__ binned) {
    __shared__ int cnt[NB_MAX];
    for (int i = threadIdx.x; i < NB; i += blockDim.x)
        cnt[i] = binBase[i] + histA[(size_t)blockIdx.x * NB + i];
    __syncthreads();
    bool is64 = (*flag == 0u);
    int base = blockIdx.x * CHUNK;
    int lim  = min(base + CHUNK, E);
    for (int e = base + threadIdx.x; e < lim; e += blockDim.x) {
        unsigned int s, t;
        load_edge(idx, e, E, is64, s, t);
        int pos = atomicAdd(&cnt[t >> 7], 1);
        nts_u(binned + pos, s | ((t & 127u) << 20));
    }
}

// Pass D: per-bin counting sort by low 7 target bits -> CSR.
__global__ void k_sort2(const unsigned int* __restrict__ binned,
                        const int* __restrict__ binBase,
                        const int* __restrict__ binTotal,
                        unsigned int* __restrict__ sortedSrc,
                        int* __restrict__ rowPtr, int N, int NB) {
    __shared__ int cnt[NPB];
    __shared__ int scn[NPB];
    int b = blockIdx.x;
    int node0 = b << 7;
    int start = binBase[b], total = binTotal[b];
    int i = threadIdx.x;

    if (i < NPB) cnt[i] = 0;
    __syncthreads();
    for (int e = i; e < total; e += blockDim.x)
        atomicAdd(&cnt[ntl_u(binned + start + e) >> 20], 1);
    __syncthreads();

    if (i < NPB) scn[i] = cnt[i];
    __syncthreads();
    for (int off = 1; off < NPB; off <<= 1) {
        int t = (i < NPB && i >= off) ? scn[i - off] : 0;
        __syncthreads();
        if (i < NPB) scn[i] += t;
        __syncthreads();
    }
    if (i < NPB) {
        int excl = scn[i] - cnt[i];
        cnt[i] = excl;
        int n = node0 + i;
        if (n < N) rowPtr[n] = start + excl;
    }
    if (b == NB - 1 && i == 0) rowPtr[N] = start + total;
    __syncthreads();

    for (int e = i; e < total; e += blockDim.x) {
        unsigned int v = ntl_u(binned + start + e);
        int pos = atomicAdd(&cnt[v >> 20], 1);
        nts_u(sortedSrc + start + pos, v & 0xFFFFFu);
    }
}

// ---------------------------------------------------------------------------
// Pass E: per-node sums via contiguous edge runs; emits fused combo record
// combo[t] = { strg half[8], 1/sum half[8] }  (32 B, one gather in edge_out).
__global__ void k_nodesum(const unsigned int* __restrict__ sortedSrc,
                          const int* __restrict__ rowPtr,
                          const __half* __restrict__ ssrc_h,
                          const float* __restrict__ strg_f,
                          __half* __restrict__ combo, int N) {
    int gt = blockIdx.x * blockDim.x + threadIdx.x;
    int n  = gt >> 3;           // TPN = 8
    int k  = gt & (TPN - 1);
    if (n >= N) return;

    int r0 = rowPtr[n], r1 = rowPtr[n + 1];
    const float4* tp = (const float4*)(strg_f + (size_t)n * HEADS);
    float4 ta = tp[0], tb = tp[1];
    float st[8] = { ta.x, ta.y, ta.z, ta.w, tb.x, tb.y, tb.z, tb.w };
    float acc[8] = { 0, 0, 0, 0, 0, 0, 0, 0 };

    for (int e = r0 + k; e < r1; e += TPN) {
        unsigned int s = ntl_u(sortedSrc + e);
        uint4 sv = *(const uint4*)(ssrc_h + (size_t)s * HEADS);
        float2 f01 = up2(sv.x), f23 = up2(sv.y), f45 = up2(sv.z), f67 = up2(sv.w);
        float vs[8] = { f01.x, f01.y, f23.x, f23.y, f45.x, f45.y, f67.x, f67.y };
        #pragma unroll
        for (int h = 0; h < HEADS; ++h) {
            float sc = vs[h] + st[h];
            sc = sc > 0.f ? sc : 0.2f * sc;
            acc[h] += expf(sc);
        }
    }
    #pragma unroll
    for (int h = 0; h < HEADS; ++h) {
        acc[h] += __shfl_xor(acc[h], 1, 64);
        acc[h] += __shfl_xor(acc[h], 2, 64);
        acc[h] += __shfl_xor(acc[h], 4, 64);
    }
    if (k == 0) {
        float rs[8];
        #pragma unroll
        for (int h = 0; h < HEADS; ++h) rs[h] = 1.0f / (acc[h] + 1e-16f);
        uint4 c0, c1;
        c0.x = pack2(st[0], st[1]);  c0.y = pack2(st[2], st[3]);
        c0.z = pack2(st[4], st[5]);  c0.w = pack2(st[6], st[7]);
        c1.x = pack2(rs[0], rs[1]);  c1.y = pack2(rs[2], rs[3]);
        c1.z = pack2(rs[4], rs[5]);  c1.w = pack2(rs[6], rs[7]);
        uint4* cp = (uint4*)(combo + (size_t)n * 16);
        cp[0] = c0;
        cp[1] = c1;
    }
}

// ---------------------------------------------------------------------------
// Fast edge output: 2 gathers (16B ssrc_h, 32B combo) over a 4.8 MB hot set.
// idx loads + out stores are non-temporal (streaming) to protect that set.
__global__ void k_edge_out_c(const unsigned int* __restrict__ idx, int E,
                             const __half* __restrict__ ssrc_h,
                             const __half* __restrict__ combo,
                             const unsigned int* __restrict__ flag,
                             float* __restrict__ out) {
    int e = blockIdx.x * blockDim.x + threadIdx.x;
    if (e >= E) return;
    bool is64 = (*flag == 0u);
    unsigned int s, t;
    load_edge(idx, e, E, is64, s, t);

    uint4 sv = *(const uint4*)(ssrc_h + (size_t)s * HEADS);
    const uint4* cp = (const uint4*)(combo + (size_t)t * 16);
    uint4 c0 = cp[0], c1 = cp[1];

    float2 s01 = up2(sv.x), s23 = up2(sv.y), s45 = up2(sv.z), s67 = up2(sv.w);
    float2 t01 = up2(c0.x), t23 = up2(c0.y), t45 = up2(c0.z), t67 = up2(c0.w);
    float2 r01 = up2(c1.x), r23 = up2(c1.y), r45 = up2(c1.z), r67 = up2(c1.w);

    float ss[8] = { s01.x, s01.y, s23.x, s23.y, s45.x, s45.y, s67.x, s67.y };
    float st[8] = { t01.x, t01.y, t23.x, t23.y, t45.x, t45.y, t67.x, t67.y };
    float rs[8] = { r01.x, r01.y, r23.x, r23.y, r45.x, r45.y, r67.x, r67.y };

    float o[8];
    #pragma unroll
    for (int h = 0; h < HEADS; ++h) {
        float sc = ss[h] + st[h];
        sc = sc > 0.f ? sc : 0.2f * sc;
        o[h] = expf(sc) * rs[h];
    }
    float4v o0 = { o[0], o[1], o[2], o[3] };
    float4v o1 = { o[4], o[5], o[6], o[7] };
    nts_f4(out + (size_t)e * HEADS,     o0);
    nts_f4(out + (size_t)e * HEADS + 4, o1);
}

// ---------------------------------------------------------------------------
// Fallback path (device atomics + fp32), used only if workspace too small.
__device__ __forceinline__ void edge_scores(const float* ssrc, const float* strg,
                                            unsigned int s, unsigned int t, float* ex) {
    const float4* sp = (const float4*)(ssrc + (size_t)s * HEADS);
    const float4* tp = (const float4*)(strg + (size_t)t * HEADS);
    float4 sa = sp[0], sb = sp[1], ta = tp[0], tb = tp[1];
    float v[8] = { sa.x + ta.x, sa.y + ta.y, sa.z + ta.z, sa.w + ta.w,
                   sb.x + tb.x, sb.y + tb.y, sb.z + tb.z, sb.w + tb.w };
    #pragma unroll
    for (int h = 0; h < HEADS; ++h) {
        float sc = v[h];
        sc = sc > 0.f ? sc : 0.2f * sc;
        ex[h] = expf(sc);
    }
}

__global__ void k_edge_sum(const unsigned int* __restrict__ idx, int E,
                           const float* __restrict__ ssrc,
                           const float* __restrict__ strg,
                           float* __restrict__ sums,
                           const unsigned int* __restrict__ flag) {
    int e = blockIdx.x * blockDim.x + threadIdx.x;
    if (e >= E) return;
    bool is64 = (*flag == 0u);
    unsigned int s, t;
    load_edge(idx, e, E, is64, s, t);
    float ex[8];
    edge_scores(ssrc, strg, s, t, ex);
    float* dst = sums + (size_t)t * HEADS;
    #pragma unroll
    for (int h = 0; h < HEADS; ++h)
        atomicAdd(dst + h, ex[h]);
}

__global__ void k_edge_out(const unsigned int* __restrict__ idx, int E,
                           const float* __restrict__ ssrc,
                           const float* __restrict__ strg,
                           const float* __restrict__ sums,
                           const unsigned int* __restrict__ flag,
                           float* __restrict__ out) {
    int e = blockIdx.x * blockDim.x + threadIdx.x;
    if (e >= E) return;
    bool is64 = (*flag == 0u);
    unsigned int s, t;
    load_edge(idx, e, E, is64, s, t);
    float ex[8];
    edge_scores(ssrc, strg, s, t, ex);
    const float4* sm = (const float4*)(sums + (size_t)t * HEADS);
    float4 m0 = sm[0], m1 = sm[1];
    float4 o0, o1;
    o0.x = ex[0] / (m0.x + 1e-16f);  o0.y = ex[1] / (m0.y + 1e-16f);
    o0.z = ex[2] / (m0.z + 1e-16f);  o0.w = ex[3] / (m0.w + 1e-16f);
    o1.x = ex[4] / (m1.x + 1e-16f);  o1.y = ex[5] / (m1.y + 1e-16f);
    o1.z = ex[6] / (m1.z + 1e-16f);  o1.w = ex[7] / (m1.w + 1e-16f);
    float4* op = (float4*)(out + (size_t)e * HEADS);
    op[0] = o0;
    op[1] = o1;
}

// ---------------------------------------------------------------------------
extern "C" void kernel_launch(void* const* d_in, const int* in_sizes, int n_in,
                              void* d_out, int out_size, void* d_ws, size_t ws_size,
                              hipStream_t stream) {
    const float*        x     = (const float*)d_in[0];
    const float*        W     = (const float*)d_in[1];
    const float*        a_src = (const float*)d_in[2];
    const float*        a_trg = (const float*)d_in[3];
    const unsigned int* idx   = (const unsigned int*)d_in[4];

    const int N  = in_sizes[0] / D_IN;   // 100000
    const int E  = in_sizes[4] / 2;      // 3200000
    const int NH = N * HEADS;
    const int NB   = (N + NPB - 1) / NPB;     // 782
    const int NBLK = (E + CHUNK - 1) / CHUNK; // 782

    float* out = (float*)d_out;

    // workspace layout (256B-aligned segments)
    char*  ws  = (char*)d_ws;
    size_t off = 0;
    auto alloc = [&](size_t bytes) { size_t o = off; off = (off + bytes + 255) & ~(size_t)255; return o; };
    size_t NHb = (size_t)NH * sizeof(float);
    float*        sums     = (float*)(ws + alloc(NHb));                 // fallback only
    unsigned int* flag     = (unsigned int*)(ws + alloc(4));
    float*        ssrc_f   = (float*)(ws + alloc(NHb));
    float*        strg_f   = (float*)(ws + alloc(NHb));
    __half*       ssrc_h   = (__half*)(ws + alloc((size_t)NH * sizeof(__half)));
    __half*       combo    = (__half*)(ws + alloc((size_t)N * 16 * sizeof(__half)));
    float*        Wc       = (float*)(ws + alloc(NOUT * D_IN * sizeof(float)));
    int*          histA    = (int*)(ws + alloc((size_t)NBLK * NB * sizeof(int)));
    int*          histB    = (int*)(ws + alloc((size_t)NB * NBLK * sizeof(int)));
    int*          binTotal = (int*)(ws + alloc((size_t)NB * sizeof(int)));
    int*          binBase  = (int*)(ws + alloc((size_t)NB * sizeof(int)));
    unsigned int* binned   = (unsigned int*)(ws + alloc((size_t)E * sizeof(unsigned int)));
    unsigned int* sortedS  = (unsigned int*)(ws + alloc((size_t)E * sizeof(unsigned int)));
    int*          rowPtr   = (int*)(ws + alloc((size_t)(N + 1) * sizeof(int)));

    const bool fast = (off <= ws_size) && (NB <= NB_MAX) && (NBLK <= NBLK_MAX)
                      && (N < (1 << 20));

    if (!fast)
        hipMemsetAsync(sums, 0, NHb, stream);

    // k_fold_w zeroes flag; runs before k_detect on the same stream.
    k_fold_w <<<(D_IN * HEADS + 255) / 256, 256, 0, stream>>>(W, a_src, a_trg, Wc, flag);

    int dwords = in_sizes[4];
    if (dwords > (1 << 20)) dwords = 1 << 20;   // sampled detection is sufficient
    k_detect <<<128, 256, 0, stream>>>(idx, dwords, flag);

    k_scores_t <<<(N + SROWS - 1) / SROWS, 256, 0, stream>>>(x, Wc, ssrc_f, strg_f,
                                                             ssrc_h, N);

    int eblocks = (E + 255) / 256;
    if (fast) {
        k_hist        <<<NBLK, 512, 0, stream>>>(idx, E, flag, histB, NB, NBLK);
        k_scan_blocks <<<NB, NBLK_MAX, 0, stream>>>(histB, histA, NB, NBLK, binTotal);
        k_scan_bins   <<<1, NB_MAX, 0, stream>>>(binTotal, NB, binBase);
        k_scatter     <<<NBLK, 512, 0, stream>>>(idx, E, flag, histA, NB, binBase, binned);
        k_sort2       <<<NB, 512, 0, stream>>>(binned, binBase, binTotal, sortedS,
                                               rowPtr, N, NB);
        k_nodesum     <<<(N * TPN + 511) / 512, 512, 0, stream>>>(sortedS, rowPtr,
                                                                  ssrc_h, strg_f,
                                                                  combo, N);
        k_edge_out_c  <<<eblocks, 256, 0, stream>>>(idx, E, ssrc_h, combo, flag, out);
    } else {
        k_edge_sum <<<eblocks, 256, 0, stream>>>(idx, E, ssrc_f, strg_f, sums, flag);
        k_edge_out <<<eblocks, 256, 0, stream>>>(idx, E, ssrc_f, strg_f, sums, flag, out);
    }
}

// Round 9
// 261.422 us; speedup vs baseline: 1.3019x; 1.3019x over previous
//
#include <hip/hip_runtime.h>
#include <hip/hip_fp16.h>

#define D_IN   128
#define HEADS  8
#define FOUT   64
#define NOUT   16     // 8 src + 8 trg folded outputs
#define NPB    128    // nodes per bin (local index fits in 7 bits)
#define NB_MAX 1024   // max bins
#define CHUNK  4096   // edges per histogram/scatter block
#define NBLK_MAX 1024 // max blocks in pass A/C (scan width)
#define TPN    8      // threads per node in k_nodesum
#define SROWS  64     // nodes per k_scores tile
#define SPAD   129    // padded LDS row stride (floats)

typedef unsigned __attribute__((ext_vector_type(2))) uint2v;
typedef float    __attribute__((ext_vector_type(4))) float4v;

// -------------------------------- helpers -----------------------------------
__device__ __forceinline__ unsigned pack2(float a, float b) {
    union { __half2 h; unsigned u; } c;
    c.h = __floats2half2_rn(a, b);
    return c.u;
}
__device__ __forceinline__ float2 up2(unsigned u) {
    union { unsigned x; __half2 h; } c;
    c.x = u;
    return __half22float2(c.h);
}

// Non-temporal ONLY for dense read-once (idx, x) and dense write-once (out)
// streams. NEVER for scattered stores or producer->consumer intermediates:
// r8 showed nt on scattered 4B stores defeats L2 write-combining
// (k_scatter WRITE_SIZE 13 MB -> 89 MB, 25 us -> 100 us).
__device__ __forceinline__ unsigned ntl_u(const unsigned* p) {
    return __builtin_nontemporal_load(p);
}
__device__ __forceinline__ uint2v ntl_u2(const unsigned* p) {
    return __builtin_nontemporal_load((const uint2v*)p);
}
__device__ __forceinline__ float4v ntl_f4(const float* p) {
    return __builtin_nontemporal_load((const float4v*)p);
}
__device__ __forceinline__ void nts_f4(float* p, float4v v) {
    __builtin_nontemporal_store(v, (float4v*)p);
}

// ---------------------------------------------------------------------------
// int32 vs int64 edge_index detection (sampled): if int64 (LE), odd 32-bit
// words are zero high-halves.  flag==0 -> int64 ; flag!=0 -> int32.
// flag is zeroed by k_fold_w (launched before this on the same stream).
__global__ void k_detect(const unsigned int* __restrict__ idx_w, int nwords,
                         unsigned int* __restrict__ flag) {
    unsigned int local = 0;
    int stride = gridDim.x * blockDim.x;
    for (int i = blockIdx.x * blockDim.x + threadIdx.x; 2 * i + 1 < nwords; i += stride)
        local |= idx_w[2 * i + 1];
    if (__any(local != 0) && (threadIdx.x & 63) == 0)
        atomicOr(flag, 1u);
}

__device__ __forceinline__ void load_edge(const unsigned int* idx, int e, int E,
                                          bool is64, unsigned int& s, unsigned int& t) {
    if (is64) {
        uint2v a = ntl_u2(idx + 2 * (size_t)e);
        uint2v b = ntl_u2(idx + 2 * ((size_t)E + e));
        s = a.x; t = b.x;
    } else {
        s = ntl_u(idx + e);
        t = ntl_u(idx + (size_t)E + e);
    }
}

__device__ __forceinline__ unsigned int load_trg(const unsigned int* idx, int e, int E,
                                                 bool is64) {
    if (is64) { uint2v b = ntl_u2(idx + 2 * ((size_t)E + e)); return b.x; }
    return ntl_u(idx + (size_t)E + e);
}

// ---------------------------------------------------------------------------
// Fold scoring vectors into the projection. Wc layout: [16 outputs][128 d].
// Also zeroes the detection flag (replaces a hipMemsetAsync that cost ~60us
// of GPU time per graph replay as a fillBufferAligned dispatch).
__global__ void k_fold_w(const float* __restrict__ W,
                         const float* __restrict__ a_src,
                         const float* __restrict__ a_trg,
                         float* __restrict__ Wc,
                         unsigned int* __restrict__ flag) {
    int t = blockIdx.x * blockDim.x + threadIdx.x;
    if (t == 0) *flag = 0u;
    if (t >= D_IN * HEADS) return;
    int d = t >> 3, h = t & 7;
    const float* wrow = W + d * (HEADS * FOUT) + h * FOUT;
    float s1 = 0.f, s2 = 0.f;
    #pragma unroll 4
    for (int f = 0; f < FOUT; ++f) {
        float w = wrow[f];
        s1 += w * a_src[h * FOUT + f];
        s2 += w * a_trg[h * FOUT + f];
    }
    Wc[h * D_IN + d]           = s1;
    Wc[(HEADS + h) * D_IN + d] = s2;
}

// ---------------------------------------------------------------------------
// Per-node scores, shuffle-free: stage 64 X-rows in LDS (stride-129 pad),
// thread (r, og) computes outputs og*4..og*4+3 for node r.
__global__ void k_scores_t(const float* __restrict__ x,
                           const float* __restrict__ Wc,
                           float* __restrict__ ssrc_f,
                           float* __restrict__ strg_f,
                           __half* __restrict__ ssrc_h, int N) {
    __shared__ float xt[SROWS * SPAD];
    int node0 = blockIdx.x * SROWS;
    int tid   = threadIdx.x;
    int nrows = min(SROWS, N - node0);

    for (int i = tid; i < nrows * 32; i += 256) {
        int r = i >> 5, c = (i & 31) * 4;
        float4v v = ntl_f4(x + (size_t)(node0 + r) * D_IN + c);
        float* dst = &xt[r * SPAD + c];
        dst[0] = v.x; dst[1] = v.y; dst[2] = v.z; dst[3] = v.w;
    }
    __syncthreads();

    int r  = tid & 63;
    int og = tid >> 6;          // wave-uniform output group (4 outputs)
    if (r >= nrows) return;
    int n = node0 + r;

    const float* w = Wc + og * 4 * D_IN;
    float a0 = 0.f, a1 = 0.f, a2 = 0.f, a3 = 0.f;
    const float* xr = &xt[r * SPAD];
    #pragma unroll 8
    for (int d = 0; d < D_IN; ++d) {
        float xv = xr[d];
        a0 += xv * w[d];
        a1 += xv * w[D_IN + d];
        a2 += xv * w[2 * D_IN + d];
        a3 += xv * w[3 * D_IN + d];
    }

    float4 res = make_float4(a0, a1, a2, a3);
    if (og < 2) *(float4*)(ssrc_f + (size_t)n * HEADS + og * 4)       = res;
    else        *(float4*)(strg_f + (size_t)n * HEADS + (og - 2) * 4) = res;
    if (og < 2) {
        uint2 hp;
        hp.x = pack2(a0, a1);
        hp.y = pack2(a2, a3);
        *(uint2*)(ssrc_h + (size_t)n * HEADS + og * 4) = hp;
    }
}

// ---------------------------------------------------------------------------
// Pass A: per-block LDS histogram of coarse bins; write bin-major histB.
__global__ void k_hist(const unsigned int* __restrict__ idx, int E,
                       const unsigned int* __restrict__ flag,
                       int* __restrict__ histB, int NB, int NBLK) {
    __shared__ int h[NB_MAX];
    for (int i = threadIdx.x; i < NB; i += blockDim.x) h[i] = 0;
    __syncthreads();
    bool is64 = (*flag == 0u);
    int base = blockIdx.x * CHUNK;
    int lim  = min(base + CHUNK, E);
    for (int e = base + threadIdx.x; e < lim; e += blockDim.x) {
        unsigned int t = load_trg(idx, e, E, is64);
        atomicAdd(&h[t >> 7], 1);
    }
    __syncthreads();
    for (int i = threadIdx.x; i < NB; i += blockDim.x)
        histB[(size_t)i * NBLK + blockIdx.x] = h[i];
}

// Pass B1: per-bin exclusive scan over blocks (coalesced histB row read);
// exclusive offsets scattered into block-major histA; per-bin totals out.
__global__ void k_scan_blocks(const int* __restrict__ histB,
                              int* __restrict__ histA, int NB, int NBLK,
                              int* __restrict__ binTotal) {
    int b = blockIdx.x;
    __shared__ int v[NBLK_MAX];
    int tid = threadIdx.x;
    v[tid] = (tid < NBLK) ? histB[(size_t)b * NBLK + tid] : 0;
    __syncthreads();
    for (int off = 1; off < NBLK_MAX; off <<= 1) {
        int t = (tid >= off) ? v[tid - off] : 0;
        __syncthreads();
        v[tid] += t;
        __syncthreads();
    }
    if (tid < NBLK)
        histA[(size_t)tid * NB + b] = tid ? v[tid - 1] : 0;
    if (tid == 0)
        binTotal[b] = v[NBLK_MAX - 1];
}

// Pass B2: exclusive scan over bins. single block.
__global__ void k_scan_bins(const int* __restrict__ binTotal, int NB,
                            int* __restrict__ binBase) {
    __shared__ int v[NB_MAX];
    int tid = threadIdx.x;
    v[tid] = (tid < NB) ? binTotal[tid] : 0;
    __syncthreads();
    for (int off = 1; off < NB_MAX; off <<= 1) {
        int t = (tid >= off) ? v[tid - off] : 0;
        __syncthreads();
        v[tid] += t;
        __syncthreads();
    }
    if (tid < NB)
        binBase[tid] = tid ? v[tid - 1] : 0;
}

// Pass C: scatter packed edge records into bin order.
// record = src | (trg & 127) << 20   (needs N < 2^20)
// binned stores are REGULAR (L2 write-combines the scattered dwords).
__global__ void k_scatter(const unsigned int* __restrict__ idx, int E,
                          const unsigned int* __restrict__ flag,
                          const int* __restrict__ histA, int NB,
                          const int* __restrict__ binBase,
                          unsigned int* __restrict__ binned) {
    __shared__ int cnt[NB_MAX];
    for (int i = threadIdx.x; i < NB; i += blockDim.x)
        cnt[i] = binBase[i] + histA[(size_t)blockIdx.x * NB + i];
    __syncthreads();
    bool is64 = (*flag == 0u);
    int base = blockIdx.x * CHUNK;
    int lim  = min(base + CHUNK, E);
    for (int e = base + threadIdx.x; e < lim; e += blockDim.x) {
        unsigned int s, t;
        load_edge(idx, e, E, is64, s, t);
        int pos = atomicAdd(&cnt[t >> 7], 1);
        binned[pos] = s | ((t & 127u) << 20);
    }
}

// Pass D: per-bin counting sort by low 7 target bits -> CSR.
__global__ void k_sort2(const unsigned int* __restrict__ binned,
                        const int* __restrict__ binBase,
                        const int* __restrict__ binTotal,
                        unsigned int* __restrict__ sortedSrc,
                        int* __restrict__ rowPtr, int N, int NB) {
    __shared__ int cnt[NPB];
    __shared__ int scn[NPB];
    int b = blockIdx.x;
    int node0 = b << 7;
    int start = binBase[b], total = binTotal[b];
    int i = threadIdx.x;

    if (i < NPB) cnt[i] = 0;
    __syncthreads();
    for (int e = i; e < total; e += blockDim.x)
        atomicAdd(&cnt[binned[start + e] >> 20], 1);
    __syncthreads();

    if (i < NPB) scn[i] = cnt[i];
    __syncthreads();
    for (int off = 1; off < NPB; off <<= 1) {
        int t = (i < NPB && i >= off) ? scn[i - off] : 0;
        __syncthreads();
        if (i < NPB) scn[i] += t;
        __syncthreads();
    }
    if (i < NPB) {
        int excl = scn[i] - cnt[i];
        cnt[i] = excl;
        int n = node0 + i;
        if (n < N) rowPtr[n] = start + excl;
    }
    if (b == NB - 1 && i == 0) rowPtr[N] = start + total;
    __syncthreads();

    for (int e = i; e < total; e += blockDim.x) {
        unsigned int v = binned[start + e];
        int pos = atomicAdd(&cnt[v >> 20], 1);
        sortedSrc[start + pos] = v & 0xFFFFFu;
    }
}

// ---------------------------------------------------------------------------
// Pass E: per-node sums via contiguous edge runs; emits fused combo record
// combo[t] = { strg half[8], 1/sum half[8] }  (32 B, one gather in edge_out).
__global__ void k_nodesum(const unsigned int* __restrict__ sortedSrc,
                          const int* __restrict__ rowPtr,
                          const __half* __restrict__ ssrc_h,
                          const float* __restrict__ strg_f,
                          __half* __restrict__ combo, int N) {
    int gt = blockIdx.x * blockDim.x + threadIdx.x;
    int n  = gt >> 3;           // TPN = 8
    int k  = gt & (TPN - 1);
    if (n >= N) return;

    int r0 = rowPtr[n], r1 = rowPtr[n + 1];
    const float4* tp = (const float4*)(strg_f + (size_t)n * HEADS);
    float4 ta = tp[0], tb = tp[1];
    float st[8] = { ta.x, ta.y, ta.z, ta.w, tb.x, tb.y, tb.z, tb.w };
    float acc[8] = { 0, 0, 0, 0, 0, 0, 0, 0 };

    for (int e = r0 + k; e < r1; e += TPN) {
        unsigned int s = sortedSrc[e];
        uint4 sv = *(const uint4*)(ssrc_h + (size_t)s * HEADS);
        float2 f01 = up2(sv.x), f23 = up2(sv.y), f45 = up2(sv.z), f67 = up2(sv.w);
        float vs[8] = { f01.x, f01.y, f23.x, f23.y, f45.x, f45.y, f67.x, f67.y };
        #pragma unroll
        for (int h = 0; h < HEADS; ++h) {
            float sc = vs[h] + st[h];
            sc = sc > 0.f ? sc : 0.2f * sc;
            acc[h] += expf(sc);
        }
    }
    #pragma unroll
    for (int h = 0; h < HEADS; ++h) {
        acc[h] += __shfl_xor(acc[h], 1, 64);
        acc[h] += __shfl_xor(acc[h], 2, 64);
        acc[h] += __shfl_xor(acc[h], 4, 64);
    }
    if (k == 0) {
        float rs[8];
        #pragma unroll
        for (int h = 0; h < HEADS; ++h) rs[h] = 1.0f / (acc[h] + 1e-16f);
        uint4 c0, c1;
        c0.x = pack2(st[0], st[1]);  c0.y = pack2(st[2], st[3]);
        c0.z = pack2(st[4], st[5]);  c0.w = pack2(st[6], st[7]);
        c1.x = pack2(rs[0], rs[1]);  c1.y = pack2(rs[2], rs[3]);
        c1.z = pack2(rs[4], rs[5]);  c1.w = pack2(rs[6], rs[7]);
        uint4* cp = (uint4*)(combo + (size_t)n * 16);
        cp[0] = c0;
        cp[1] = c1;
    }
}

// ---------------------------------------------------------------------------
// Fast edge output: 2 gathers (16B ssrc_h, 32B combo) over a 4.8 MB hot set.
// idx loads + out stores are non-temporal (dense streams) to protect that set.
__global__ void k_edge_out_c(const unsigned int* __restrict__ idx, int E,
                             const __half* __restrict__ ssrc_h,
                             const __half* __restrict__ combo,
                             const unsigned int* __restrict__ flag,
                             float* __restrict__ out) {
    int e = blockIdx.x * blockDim.x + threadIdx.x;
    if (e >= E) return;
    bool is64 = (*flag == 0u);
    unsigned int s, t;
    load_edge(idx, e, E, is64, s, t);

    uint4 sv = *(const uint4*)(ssrc_h + (size_t)s * HEADS);
    const uint4* cp = (const uint4*)(combo + (size_t)t * 16);
    uint4 c0 = cp[0], c1 = cp[1];

    float2 s01 = up2(sv.x), s23 = up2(sv.y), s45 = up2(sv.z), s67 = up2(sv.w);
    float2 t01 = up2(c0.x), t23 = up2(c0.y), t45 = up2(c0.z), t67 = up2(c0.w);
    float2 r01 = up2(c1.x), r23 = up2(c1.y), r45 = up2(c1.z), r67 = up2(c1.w);

    float ss[8] = { s01.x, s01.y, s23.x, s23.y, s45.x, s45.y, s67.x, s67.y };
    float st[8] = { t01.x, t01.y, t23.x, t23.y, t45.x, t45.y, t67.x, t67.y };
    float rs[8] = { r01.x, r01.y, r23.x, r23.y, r45.x, r45.y, r67.x, r67.y };

    float o[8];
    #pragma unroll
    for (int h = 0; h < HEADS; ++h) {
        float sc = ss[h] + st[h];
        sc = sc > 0.f ? sc : 0.2f * sc;
        o[h] = expf(sc) * rs[h];
    }
    float4v o0 = { o[0], o[1], o[2], o[3] };
    float4v o1 = { o[4], o[5], o[6], o[7] };
    nts_f4(out + (size_t)e * HEADS,     o0);
    nts_f4(out + (size_t)e * HEADS + 4, o1);
}

// ---------------------------------------------------------------------------
// Fallback path (device atomics + fp32), used only if workspace too small.
__device__ __forceinline__ void edge_scores(const float* ssrc, const float* strg,
                                            unsigned int s, unsigned int t, float* ex) {
    const float4* sp = (const float4*)(ssrc + (size_t)s * HEADS);
    const float4* tp = (const float4*)(strg + (size_t)t * HEADS);
    float4 sa = sp[0], sb = sp[1], ta = tp[0], tb = tp[1];
    float v[8] = { sa.x + ta.x, sa.y + ta.y, sa.z + ta.z, sa.w + ta.w,
                   sb.x + tb.x, sb.y + tb.y, sb.z + tb.z, sb.w + tb.w };
    #pragma unroll
    for (int h = 0; h < HEADS; ++h) {
        float sc = v[h];
        sc = sc > 0.f ? sc : 0.2f * sc;
        ex[h] = expf(sc);
    }
}

__global__ void k_edge_sum(const unsigned int* __restrict__ idx, int E,
                           const float* __restrict__ ssrc,
                           const float* __restrict__ strg,
                           float* __restrict__ sums,
                           const unsigned int* __restrict__ flag) {
    int e = blockIdx.x * blockDim.x + threadIdx.x;
    if (e >= E) return;
    bool is64 = (*flag == 0u);
    unsigned int s, t;
    load_edge(idx, e, E, is64, s, t);
    float ex[8];
    edge_scores(ssrc, strg, s, t, ex);
    float* dst = sums + (size_t)t * HEADS;
    #pragma unroll
    for (int h = 0; h < HEADS; ++h)
        atomicAdd(dst + h, ex[h]);
}

__global__ void k_edge_out(const unsigned int* __restrict__ idx, int E,
                           const float* __restrict__ ssrc,
                           const float* __restrict__ strg,
                           const float* __restrict__ sums,
                           const unsigned int* __restrict__ flag,
                           float* __restrict__ out) {
    int e = blockIdx.x * blockDim.x + threadIdx.x;
    if (e >= E) return;
    bool is64 = (*flag == 0u);
    unsigned int s, t;
    load_edge(idx, e, E, is64, s, t);
    float ex[8];
    edge_scores(ssrc, strg, s, t, ex);
    const float4* sm = (const float4*)(sums + (size_t)t * HEADS);
    float4 m0 = sm[0], m1 = sm[1];
    float4 o0, o1;
    o0.x = ex[0] / (m0.x + 1e-16f);  o0.y = ex[1] / (m0.y + 1e-16f);
    o0.z = ex[2] / (m0.z + 1e-16f);  o0.w = ex[3] / (m0.w + 1e-16f);
    o1.x = ex[4] / (m1.x + 1e-16f);  o1.y = ex[5] / (m1.y + 1e-16f);
    o1.z = ex[6] / (m1.z + 1e-16f);  o1.w = ex[7] / (m1.w + 1e-16f);
    float4* op = (float4*)(out + (size_t)e * HEADS);
    op[0] = o0;
    op[1] = o1;
}

// ---------------------------------------------------------------------------
extern "C" void kernel_launch(void* const* d_in, const int* in_sizes, int n_in,
                              void* d_out, int out_size, void* d_ws, size_t ws_size,
                              hipStream_t stream) {
    const float*        x     = (const float*)d_in[0];
    const float*        W     = (const float*)d_in[1];
    const float*        a_src = (const float*)d_in[2];
    const float*        a_trg = (const float*)d_in[3];
    const unsigned int* idx   = (const unsigned int*)d_in[4];

    const int N  = in_sizes[0] / D_IN;   // 100000
    const int E  = in_sizes[4] / 2;      // 3200000
    const int NH = N * HEADS;
    const int NB   = (N + NPB - 1) / NPB;     // 782
    const int NBLK = (E + CHUNK - 1) / CHUNK; // 782

    float* out = (float*)d_out;

    // workspace layout (256B-aligned segments)
    char*  ws  = (char*)d_ws;
    size_t off = 0;
    auto alloc = [&](size_t bytes) { size_t o = off; off = (off + bytes + 255) & ~(size_t)255; return o; };
    size_t NHb = (size_t)NH * sizeof(float);
    float*        sums     = (float*)(ws + alloc(NHb));                 // fallback only
    unsigned int* flag     = (unsigned int*)(ws + alloc(4));
    float*        ssrc_f   = (float*)(ws + alloc(NHb));
    float*        strg_f   = (float*)(ws + alloc(NHb));
    __half*       ssrc_h   = (__half*)(ws + alloc((size_t)NH * sizeof(__half)));
    __half*       combo    = (__half*)(ws + alloc((size_t)N * 16 * sizeof(__half)));
    float*        Wc       = (float*)(ws + alloc(NOUT * D_IN * sizeof(float)));
    int*          histA    = (int*)(ws + alloc((size_t)NBLK * NB * sizeof(int)));
    int*          histB    = (int*)(ws + alloc((size_t)NB * NBLK * sizeof(int)));
    int*          binTotal = (int*)(ws + alloc((size_t)NB * sizeof(int)));
    int*          binBase  = (int*)(ws + alloc((size_t)NB * sizeof(int)));
    unsigned int* binned   = (unsigned int*)(ws + alloc((size_t)E * sizeof(unsigned int)));
    unsigned int* sortedS  = (unsigned int*)(ws + alloc((size_t)E * sizeof(unsigned int)));
    int*          rowPtr   = (int*)(ws + alloc((size_t)(N + 1) * sizeof(int)));

    const bool fast = (off <= ws_size) && (NB <= NB_MAX) && (NBLK <= NBLK_MAX)
                      && (N < (1 << 20));

    if (!fast)
        hipMemsetAsync(sums, 0, NHb, stream);

    // k_fold_w zeroes flag; runs before k_detect on the same stream.
    k_fold_w <<<(D_IN * HEADS + 255) / 256, 256, 0, stream>>>(W, a_src, a_trg, Wc, flag);

    int dwords = in_sizes[4];
    if (dwords > (1 << 20)) dwords = 1 << 20;   // sampled detection is sufficient
    k_detect <<<128, 256, 0, stream>>>(idx, dwords, flag);

    k_scores_t <<<(N + SROWS - 1) / SROWS, 256, 0, stream>>>(x, Wc, ssrc_f, strg_f,
                                                             ssrc_h, N);

    int eblocks = (E + 255) / 256;
    if (fast) {
        k_hist        <<<NBLK, 512, 0, stream>>>(idx, E, flag, histB, NB, NBLK);
        k_scan_blocks <<<NB, NBLK_MAX, 0, stream>>>(histB, histA, NB, NBLK, binTotal);
        k_scan_bins   <<<1, NB_MAX, 0, stream>>>(binTotal, NB, binBase);
        k_scatter     <<<NBLK, 512, 0, stream>>>(idx, E, flag, histA, NB, binBase, binned);
        k_sort2       <<<NB, 512, 0, stream>>>(binned, binBase, binTotal, sortedS,
                                               rowPtr, N, NB);
        k_nodesum     <<<(N * TPN + 511) / 512, 512, 0, stream>>>(sortedS, rowPtr,
                                                                  ssrc_h, strg_f,
                                                                  combo, N);
        k_edge_out_c  <<<eblocks, 256, 0, stream>>>(idx, E, ssrc_h, combo, flag, out);
    } else {
        k_edge_sum <<<eblocks, 256, 0, stream>>>(idx, E, ssrc_f, strg_f, sums, flag);
        k_edge_out <<<eblocks, 256, 0, stream>>>(idx, E, ssrc_f, strg_f, sums, flag, out);
    }
}

// Round 10
// 234.277 us; speedup vs baseline: 1.4528x; 1.1159x over previous
//
#include <hip/hip_runtime.h>
#include <hip/hip_fp16.h>

#define D_IN   128
#define HEADS  8
#define FOUT   64
#define NOUT   16     // 8 src + 8 trg folded outputs
#define NPB    512    // nodes per bin (local index 9 bits; src 20 + local 9 = 29 bits)
#define NPB_SH 9
#define NB_MAX 1024   // max bins
#define CHUNK  8192   // edges per histogram/scatter block (42 edges/bin/block -> full lines)
#define NBLK_MAX 1024 // max blocks in pass A/C (scan width)
#define TPN    8      // threads per node in k_nodesum
#define SROWS  64     // nodes per k_scores tile
#define SPAD   129    // padded LDS row stride (floats)

typedef unsigned __attribute__((ext_vector_type(2))) uint2v;
typedef float    __attribute__((ext_vector_type(4))) float4v;

// -------------------------------- helpers -----------------------------------
__device__ __forceinline__ unsigned pack2(float a, float b) {
    union { __half2 h; unsigned u; } c;
    c.h = __floats2half2_rn(a, b);
    return c.u;
}
__device__ __forceinline__ float2 up2(unsigned u) {
    union { unsigned x; __half2 h; } c;
    c.x = u;
    return __half22float2(c.h);
}

// Non-temporal ONLY for dense read-once (idx, x) and dense write-once (out)
// streams. NEVER for scattered stores or producer->consumer intermediates
// (r8: nt scattered stores defeat L2 write-combining, 13->89 MB).
__device__ __forceinline__ unsigned ntl_u(const unsigned* p) {
    return __builtin_nontemporal_load(p);
}
__device__ __forceinline__ uint2v ntl_u2(const unsigned* p) {
    return __builtin_nontemporal_load((const uint2v*)p);
}
__device__ __forceinline__ float4v ntl_f4(const float* p) {
    return __builtin_nontemporal_load((const float4v*)p);
}
__device__ __forceinline__ void nts_f4(float* p, float4v v) {
    __builtin_nontemporal_store(v, (float4v*)p);
}

// ---------------------------------------------------------------------------
// int32 vs int64 edge_index detection (sampled).
// flag==0 -> int64 ; flag!=0 -> int32.  Zeroed by k_fold_w.
__global__ void k_detect(const unsigned int* __restrict__ idx_w, int nwords,
                         unsigned int* __restrict__ flag) {
    unsigned int local = 0;
    int stride = gridDim.x * blockDim.x;
    for (int i = blockIdx.x * blockDim.x + threadIdx.x; 2 * i + 1 < nwords; i += stride)
        local |= idx_w[2 * i + 1];
    if (__any(local != 0) && (threadIdx.x & 63) == 0)
        atomicOr(flag, 1u);
}

__device__ __forceinline__ void load_edge(const unsigned int* idx, int e, int E,
                                          bool is64, unsigned int& s, unsigned int& t) {
    if (is64) {
        uint2v a = ntl_u2(idx + 2 * (size_t)e);
        uint2v b = ntl_u2(idx + 2 * ((size_t)E + e));
        s = a.x; t = b.x;
    } else {
        s = ntl_u(idx + e);
        t = ntl_u(idx + (size_t)E + e);
    }
}

__device__ __forceinline__ unsigned int load_trg(const unsigned int* idx, int e, int E,
                                                 bool is64) {
    if (is64) { uint2v b = ntl_u2(idx + 2 * ((size_t)E + e)); return b.x; }
    return ntl_u(idx + (size_t)E + e);
}

// ---------------------------------------------------------------------------
// Fold scoring vectors into the projection. Wc layout: [16 outputs][128 d].
// Also zeroes the detection flag (a 4B hipMemsetAsync cost ~60us/replay as a
// fillBufferAligned dispatch -- r7/r8 lesson).
__global__ void k_fold_w(const float* __restrict__ W,
                         const float* __restrict__ a_src,
                         const float* __restrict__ a_trg,
                         float* __restrict__ Wc,
                         unsigned int* __restrict__ flag) {
    int t = blockIdx.x * blockDim.x + threadIdx.x;
    if (t == 0) *flag = 0u;
    if (t >= D_IN * HEADS) return;
    int d = t >> 3, h = t & 7;
    const float* wrow = W + d * (HEADS * FOUT) + h * FOUT;
    float s1 = 0.f, s2 = 0.f;
    #pragma unroll 4
    for (int f = 0; f < FOUT; ++f) {
        float w = wrow[f];
        s1 += w * a_src[h * FOUT + f];
        s2 += w * a_trg[h * FOUT + f];
    }
    Wc[h * D_IN + d]           = s1;
    Wc[(HEADS + h) * D_IN + d] = s2;
}

// ---------------------------------------------------------------------------
// Per-node scores, shuffle-free (r7): stage 64 X-rows in LDS, thread (r,og)
// computes 4 outputs for node r; Wc reads are wave-uniform -> scalar loads.
__global__ void k_scores_t(const float* __restrict__ x,
                           const float* __restrict__ Wc,
                           float* __restrict__ ssrc_f,
                           float* __restrict__ strg_f,
                           __half* __restrict__ ssrc_h, int N) {
    __shared__ float xt[SROWS * SPAD];
    int node0 = blockIdx.x * SROWS;
    int tid   = threadIdx.x;
    int nrows = min(SROWS, N - node0);

    for (int i = tid; i < nrows * 32; i += 256) {
        int r = i >> 5, c = (i & 31) * 4;
        float4v v = ntl_f4(x + (size_t)(node0 + r) * D_IN + c);
        float* dst = &xt[r * SPAD + c];
        dst[0] = v.x; dst[1] = v.y; dst[2] = v.z; dst[3] = v.w;
    }
    __syncthreads();

    int r  = tid & 63;
    int og = tid >> 6;
    if (r >= nrows) return;
    int n = node0 + r;

    const float* w = Wc + og * 4 * D_IN;
    float a0 = 0.f, a1 = 0.f, a2 = 0.f, a3 = 0.f;
    const float* xr = &xt[r * SPAD];
    #pragma unroll 8
    for (int d = 0; d < D_IN; ++d) {
        float xv = xr[d];
        a0 += xv * w[d];
        a1 += xv * w[D_IN + d];
        a2 += xv * w[2 * D_IN + d];
        a3 += xv * w[3 * D_IN + d];
    }

    float4 res = make_float4(a0, a1, a2, a3);
    if (og < 2) *(float4*)(ssrc_f + (size_t)n * HEADS + og * 4)       = res;
    else        *(float4*)(strg_f + (size_t)n * HEADS + (og - 2) * 4) = res;
    if (og < 2) {
        uint2 hp;
        hp.x = pack2(a0, a1);
        hp.y = pack2(a2, a3);
        *(uint2*)(ssrc_h + (size_t)n * HEADS + og * 4) = hp;
    }
}

// ---------------------------------------------------------------------------
// Pass A: per-block LDS histogram of coarse bins (bin = trg >> 9).
__global__ void k_hist(const unsigned int* __restrict__ idx, int E,
                       const unsigned int* __restrict__ flag,
                       int* __restrict__ histB, int NB, int NBLK) {
    __shared__ int h[NB_MAX];
    for (int i = threadIdx.x; i < NB; i += blockDim.x) h[i] = 0;
    __syncthreads();
    bool is64 = (*flag == 0u);
    int base = blockIdx.x * CHUNK;
    int lim  = min(base + CHUNK, E);
    for (int e = base + threadIdx.x; e < lim; e += blockDim.x) {
        unsigned int t = load_trg(idx, e, E, is64);
        atomicAdd(&h[t >> NPB_SH], 1);
    }
    __syncthreads();
    for (int i = threadIdx.x; i < NB; i += blockDim.x)
        histB[(size_t)i * NBLK + blockIdx.x] = h[i];
}

// Pass B1: per-bin exclusive scan over blocks (coalesced histB row read);
// exclusive offsets scattered into block-major histA; per-bin totals out.
__global__ void k_scan_blocks(const int* __restrict__ histB,
                              int* __restrict__ histA, int NB, int NBLK,
                              int* __restrict__ binTotal) {
    int b = blockIdx.x;
    __shared__ int v[NBLK_MAX];
    int tid = threadIdx.x;
    v[tid] = (tid < NBLK) ? histB[(size_t)b * NBLK + tid] : 0;
    __syncthreads();
    for (int off = 1; off < NBLK_MAX; off <<= 1) {
        int t = (tid >= off) ? v[tid - off] : 0;
        __syncthreads();
        v[tid] += t;
        __syncthreads();
    }
    if (tid < NBLK)
        histA[(size_t)tid * NB + b] = tid ? v[tid - 1] : 0;
    if (tid == 0)
        binTotal[b] = v[NBLK_MAX - 1];
}

// Pass B2: exclusive scan over bins. single block.
__global__ void k_scan_bins(const int* __restrict__ binTotal, int NB,
                            int* __restrict__ binBase) {
    __shared__ int v[NB_MAX];
    int tid = threadIdx.x;
    v[tid] = (tid < NB) ? binTotal[tid] : 0;
    __syncthreads();
    for (int off = 1; off < NB_MAX; off <<= 1) {
        int t = (tid >= off) ? v[tid - off] : 0;
        __syncthreads();
        v[tid] += t;
        __syncthreads();
    }
    if (tid < NB)
        binBase[tid] = tid ? v[tid - 1] : 0;
}

// Pass C: scatter packed edge records into bin order.
// record = src | (trg & 511) << 20   (needs N < 2^20)
// With CHUNK/NB ~ 42 edges per (block,bin), each write run spans ~168 B ->
// near-full 128B lines, killing the r9 5.8x write amplification.
__global__ void k_scatter(const unsigned int* __restrict__ idx, int E,
                          const unsigned int* __restrict__ flag,
                          const int* __restrict__ histA, int NB,
                          const int* __restrict__ binBase,
                          unsigned int* __restrict__ binned) {
    __shared__ int cnt[NB_MAX];
    for (int i = threadIdx.x; i < NB; i += blockDim.x)
        cnt[i] = binBase[i] + histA[(size_t)blockIdx.x * NB + i];
    __syncthreads();
    bool is64 = (*flag == 0u);
    int base = blockIdx.x * CHUNK;
    int lim  = min(base + CHUNK, E);
    for (int e = base + threadIdx.x; e < lim; e += blockDim.x) {
        unsigned int s, t;
        load_edge(idx, e, E, is64, s, t);
        int pos = atomicAdd(&cnt[t >> NPB_SH], 1);
        binned[pos] = s | ((t & (NPB - 1u)) << 20);
    }
}

// Pass D: per-bin counting sort by low 9 target bits -> CSR. 512 threads.
__global__ void k_sort2(const unsigned int* __restrict__ binned,
                        const int* __restrict__ binBase,
                        const int* __restrict__ binTotal,
                        unsigned int* __restrict__ sortedSrc,
                        int* __restrict__ rowPtr, int N, int NB) {
    __shared__ int cnt[NPB];
    __shared__ int scn[NPB];
    int b = blockIdx.x;
    int node0 = b << NPB_SH;
    int start = binBase[b], total = binTotal[b];
    int i = threadIdx.x;

    cnt[i] = 0;
    __syncthreads();
    for (int e = i; e < total; e += blockDim.x)
        atomicAdd(&cnt[binned[start + e] >> 20], 1);
    __syncthreads();

    scn[i] = cnt[i];
    __syncthreads();
    for (int off = 1; off < NPB; off <<= 1) {
        int t = (i >= off) ? scn[i - off] : 0;
        __syncthreads();
        scn[i] += t;
        __syncthreads();
    }
    {
        int excl = scn[i] - cnt[i];
        cnt[i] = excl;
        int n = node0 + i;
        if (n < N) rowPtr[n] = start + excl;
    }
    if (b == NB - 1 && i == 0) rowPtr[N] = start + total;
    __syncthreads();

    for (int e = i; e < total; e += blockDim.x) {
        unsigned int v = binned[start + e];
        int pos = atomicAdd(&cnt[v >> 20], 1);
        sortedSrc[start + pos] = v & 0xFFFFFu;
    }
}

// ---------------------------------------------------------------------------
// Pass E: per-node sums via contiguous edge runs; emits fused combo record
// combo[t] = { strg half[8], 1/sum half[8] }  (32 B, one gather in edge_out).
__global__ void k_nodesum(const unsigned int* __restrict__ sortedSrc,
                          const int* __restrict__ rowPtr,
                          const __half* __restrict__ ssrc_h,
                          const float* __restrict__ strg_f,
                          __half* __restrict__ combo, int N) {
    int gt = blockIdx.x * blockDim.x + threadIdx.x;
    int n  = gt >> 3;           // TPN = 8
    int k  = gt & (TPN - 1);
    if (n >= N) return;

    int r0 = rowPtr[n], r1 = rowPtr[n + 1];
    const float4* tp = (const float4*)(strg_f + (size_t)n * HEADS);
    float4 ta = tp[0], tb = tp[1];
    float st[8] = { ta.x, ta.y, ta.z, ta.w, tb.x, tb.y, tb.z, tb.w };
    float acc[8] = { 0, 0, 0, 0, 0, 0, 0, 0 };

    for (int e = r0 + k; e < r1; e += TPN) {
        unsigned int s = sortedSrc[e];
        uint4 sv = *(const uint4*)(ssrc_h + (size_t)s * HEADS);
        float2 f01 = up2(sv.x), f23 = up2(sv.y), f45 = up2(sv.z), f67 = up2(sv.w);
        float vs[8] = { f01.x, f01.y, f23.x, f23.y, f45.x, f45.y, f67.x, f67.y };
        #pragma unroll
        for (int h = 0; h < HEADS; ++h) {
            float sc = vs[h] + st[h];
            sc = sc > 0.f ? sc : 0.2f * sc;
            acc[h] += expf(sc);
        }
    }
    #pragma unroll
    for (int h = 0; h < HEADS; ++h) {
        acc[h] += __shfl_xor(acc[h], 1, 64);
        acc[h] += __shfl_xor(acc[h], 2, 64);
        acc[h] += __shfl_xor(acc[h], 4, 64);
    }
    if (k == 0) {
        float rs[8];
        #pragma unroll
        for (int h = 0; h < HEADS; ++h) rs[h] = 1.0f / (acc[h] + 1e-16f);
        uint4 c0, c1;
        c0.x = pack2(st[0], st[1]);  c0.y = pack2(st[2], st[3]);
        c0.z = pack2(st[4], st[5]);  c0.w = pack2(st[6], st[7]);
        c1.x = pack2(rs[0], rs[1]);  c1.y = pack2(rs[2], rs[3]);
        c1.z = pack2(rs[4], rs[5]);  c1.w = pack2(rs[6], rs[7]);
        uint4* cp = (uint4*)(combo + (size_t)n * 16);
        cp[0] = c0;
        cp[1] = c1;
    }
}

// ---------------------------------------------------------------------------
// Fast edge output, dual-edge per thread: two independent gather chains in
// flight hide L2-gather latency. idx/out are nt (dense streams).
__device__ __forceinline__ void edge_out_one(unsigned int s, unsigned int t,
                                             const __half* __restrict__ ssrc_h,
                                             const __half* __restrict__ combo,
                                             float* o) {
    uint4 sv = *(const uint4*)(ssrc_h + (size_t)s * HEADS);
    const uint4* cp = (const uint4*)(combo + (size_t)t * 16);
    uint4 c0 = cp[0], c1 = cp[1];
    float2 s01 = up2(sv.x), s23 = up2(sv.y), s45 = up2(sv.z), s67 = up2(sv.w);
    float2 t01 = up2(c0.x), t23 = up2(c0.y), t45 = up2(c0.z), t67 = up2(c0.w);
    float2 r01 = up2(c1.x), r23 = up2(c1.y), r45 = up2(c1.z), r67 = up2(c1.w);
    float ss[8] = { s01.x, s01.y, s23.x, s23.y, s45.x, s45.y, s67.x, s67.y };
    float st[8] = { t01.x, t01.y, t23.x, t23.y, t45.x, t45.y, t67.x, t67.y };
    float rs[8] = { r01.x, r01.y, r23.x, r23.y, r45.x, r45.y, r67.x, r67.y };
    #pragma unroll
    for (int h = 0; h < HEADS; ++h) {
        float sc = ss[h] + st[h];
        sc = sc > 0.f ? sc : 0.2f * sc;
        o[h] = expf(sc) * rs[h];
    }
}

__global__ void k_edge_out_c(const unsigned int* __restrict__ idx, int E,
                             const __half* __restrict__ ssrc_h,
                             const __half* __restrict__ combo,
                             const unsigned int* __restrict__ flag,
                             float* __restrict__ out) {
    int i = blockIdx.x * blockDim.x + threadIdx.x;
    int half = (E + 1) >> 1;
    if (i >= half) return;
    bool is64 = (*flag == 0u);

    int e0 = i;
    int e1 = i + half;
    bool v1 = e1 < E;
    int e1c = v1 ? e1 : e0;

    unsigned int s0, t0, s1, t1;
    load_edge(idx, e0, E, is64, s0, t0);
    load_edge(idx, e1c, E, is64, s1, t1);

    float o0[8], o1[8];
    edge_out_one(s0, t0, ssrc_h, combo, o0);
    edge_out_one(s1, t1, ssrc_h, combo, o1);

    float4v a0 = { o0[0], o0[1], o0[2], o0[3] };
    float4v a1 = { o0[4], o0[5], o0[6], o0[7] };
    nts_f4(out + (size_t)e0 * HEADS,     a0);
    nts_f4(out + (size_t)e0 * HEADS + 4, a1);
    if (v1) {
        float4v b0 = { o1[0], o1[1], o1[2], o1[3] };
        float4v b1 = { o1[4], o1[5], o1[6], o1[7] };
        nts_f4(out + (size_t)e1 * HEADS,     b0);
        nts_f4(out + (size_t)e1 * HEADS + 4, b1);
    }
}

// ---------------------------------------------------------------------------
// Fallback path (device atomics + fp32), used only if workspace too small.
__device__ __forceinline__ void edge_scores(const float* ssrc, const float* strg,
                                            unsigned int s, unsigned int t, float* ex) {
    const float4* sp = (const float4*)(ssrc + (size_t)s * HEADS);
    const float4* tp = (const float4*)(strg + (size_t)t * HEADS);
    float4 sa = sp[0], sb = sp[1], ta = tp[0], tb = tp[1];
    float v[8] = { sa.x + ta.x, sa.y + ta.y, sa.z + ta.z, sa.w + ta.w,
                   sb.x + tb.x, sb.y + tb.y, sb.z + tb.z, sb.w + tb.w };
    #pragma unroll
    for (int h = 0; h < HEADS; ++h) {
        float sc = v[h];
        sc = sc > 0.f ? sc : 0.2f * sc;
        ex[h] = expf(sc);
    }
}

__global__ void k_edge_sum(const unsigned int* __restrict__ idx, int E,
                           const float* __restrict__ ssrc,
                           const float* __restrict__ strg,
                           float* __restrict__ sums,
                           const unsigned int* __restrict__ flag) {
    int e = blockIdx.x * blockDim.x + threadIdx.x;
    if (e >= E) return;
    bool is64 = (*flag == 0u);
    unsigned int s, t;
    load_edge(idx, e, E, is64, s, t);
    float ex[8];
    edge_scores(ssrc, strg, s, t, ex);
    float* dst = sums + (size_t)t * HEADS;
    #pragma unroll
    for (int h = 0; h < HEADS; ++h)
        atomicAdd(dst + h, ex[h]);
}

__global__ void k_edge_out(const unsigned int* __restrict__ idx, int E,
                           const float* __restrict__ ssrc,
                           const float* __restrict__ strg,
                           const float* __restrict__ sums,
                           const unsigned int* __restrict__ flag,
                           float* __restrict__ out) {
    int e = blockIdx.x * blockDim.x + threadIdx.x;
    if (e >= E) return;
    bool is64 = (*flag == 0u);
    unsigned int s, t;
    load_edge(idx, e, E, is64, s, t);
    float ex[8];
    edge_scores(ssrc, strg, s, t, ex);
    const float4* sm = (const float4*)(sums + (size_t)t * HEADS);
    float4 m0 = sm[0], m1 = sm[1];
    float4 o0, o1;
    o0.x = ex[0] / (m0.x + 1e-16f);  o0.y = ex[1] / (m0.y + 1e-16f);
    o0.z = ex[2] / (m0.z + 1e-16f);  o0.w = ex[3] / (m0.w + 1e-16f);
    o1.x = ex[4] / (m1.x + 1e-16f);  o1.y = ex[5] / (m1.y + 1e-16f);
    o1.z = ex[6] / (m1.z + 1e-16f);  o1.w = ex[7] / (m1.w + 1e-16f);
    float4* op = (float4*)(out + (size_t)e * HEADS);
    op[0] = o0;
    op[1] = o1;
}

// ---------------------------------------------------------------------------
extern "C" void kernel_launch(void* const* d_in, const int* in_sizes, int n_in,
                              void* d_out, int out_size, void* d_ws, size_t ws_size,
                              hipStream_t stream) {
    const float*        x     = (const float*)d_in[0];
    const float*        W     = (const float*)d_in[1];
    const float*        a_src = (const float*)d_in[2];
    const float*        a_trg = (const float*)d_in[3];
    const unsigned int* idx   = (const unsigned int*)d_in[4];

    const int N  = in_sizes[0] / D_IN;   // 100000
    const int E  = in_sizes[4] / 2;      // 3200000
    const int NH = N * HEADS;
    const int NB   = (N + NPB - 1) / NPB;     // 196
    const int NBLK = (E + CHUNK - 1) / CHUNK; // 391

    float* out = (float*)d_out;

    // workspace layout (256B-aligned segments)
    char*  ws  = (char*)d_ws;
    size_t off = 0;
    auto alloc = [&](size_t bytes) { size_t o = off; off = (off + bytes + 255) & ~(size_t)255; return o; };
    size_t NHb = (size_t)NH * sizeof(float);
    float*        sums     = (float*)(ws + alloc(NHb));                 // fallback only
    unsigned int* flag     = (unsigned int*)(ws + alloc(4));
    float*        ssrc_f   = (float*)(ws + alloc(NHb));
    float*        strg_f   = (float*)(ws + alloc(NHb));
    __half*       ssrc_h   = (__half*)(ws + alloc((size_t)NH * sizeof(__half)));
    __half*       combo    = (__half*)(ws + alloc((size_t)N * 16 * sizeof(__half)));
    float*        Wc       = (float*)(ws + alloc(NOUT * D_IN * sizeof(float)));
    int*          histA    = (int*)(ws + alloc((size_t)NBLK * NB * sizeof(int)));
    int*          histB    = (int*)(ws + alloc((size_t)NB * NBLK * sizeof(int)));
    int*          binTotal = (int*)(ws + alloc((size_t)NB * sizeof(int)));
    int*          binBase  = (int*)(ws + alloc((size_t)NB * sizeof(int)));
    unsigned int* binned   = (unsigned int*)(ws + alloc((size_t)E * sizeof(unsigned int)));
    unsigned int* sortedS  = (unsigned int*)(ws + alloc((size_t)E * sizeof(unsigned int)));
    int*          rowPtr   = (int*)(ws + alloc((size_t)(N + 1) * sizeof(int)));

    const bool fast = (off <= ws_size) && (NB <= NB_MAX) && (NBLK <= NBLK_MAX)
                      && (N < (1 << 20));

    if (!fast)
        hipMemsetAsync(sums, 0, NHb, stream);

    // k_fold_w zeroes flag; runs before k_detect on the same stream.
    k_fold_w <<<(D_IN * HEADS + 255) / 256, 256, 0, stream>>>(W, a_src, a_trg, Wc, flag);

    int dwords = in_sizes[4];
    if (dwords > (1 << 20)) dwords = 1 << 20;   // sampled detection is sufficient
    k_detect <<<128, 256, 0, stream>>>(idx, dwords, flag);

    k_scores_t <<<(N + SROWS - 1) / SROWS, 256, 0, stream>>>(x, Wc, ssrc_f, strg_f,
                                                             ssrc_h, N);

    if (fast) {
        k_hist        <<<NBLK, 512, 0, stream>>>(idx, E, flag, histB, NB, NBLK);
        k_scan_blocks <<<NB, NBLK_MAX, 0, stream>>>(histB, histA, NB, NBLK, binTotal);
        k_scan_bins   <<<1, NB_MAX, 0, stream>>>(binTotal, NB, binBase);
        k_scatter     <<<NBLK, 512, 0, stream>>>(idx, E, flag, histA, NB, binBase, binned);
        k_sort2       <<<NB, NPB, 0, stream>>>(binned, binBase, binTotal, sortedS,
                                               rowPtr, N, NB);
        k_nodesum     <<<(N * TPN + 511) / 512, 512, 0, stream>>>(sortedS, rowPtr,
                                                                  ssrc_h, strg_f,
                                                                  combo, N);
        int half = (E + 1) >> 1;
        k_edge_out_c  <<<(half + 255) / 256, 256, 0, stream>>>(idx, E, ssrc_h, combo,
                                                               flag, out);
    } else {
        int eblocks = (E + 255) / 256;
        k_edge_sum <<<eblocks, 256, 0, stream>>>(idx, E, ssrc_f, strg_f, sums, flag);
        k_edge_out <<<eblocks, 256, 0, stream>>>(idx, E, ssrc_f, strg_f, sums, flag, out);
    }
}